// Round 6
// baseline (50.450 us; speedup 1.0000x reference)
//
#include <hip/hip_runtime.h>
#include <hip/hip_bf16.h>

// Q8_0-style fused dequant + linear: y[32,11008] = x[32,4096] @ W^T + bias
// W[o,i] = (qweight[o,i] - 127) * scales[o, i/32]
//
// Round 6: round-5 structure, tuned.
//  - NSPLIT 16->8 (halves partial traffic), KT=512, 8-chunk / 3-buffer
//    register pipeline, barrier-free W streaming (each weight read once).
//  - x slice staged once in swizzled LDS (32 KB), single __syncthreads.
//  - partials: nontemporal stores; reduce kernel float4 + nontemporal loads.
//  - NO nontemporal on W: lane's 32-B run is split over two 16-B loads, and
//    no-allocate would refetch the sector for the second (2x W traffic).

#define O_DIM  11008
#define I_DIM  4096
#define NB     128                // scale blocks per o-row
#define B_DIM  32
#define NSPLIT 8
#define KT     (I_DIM / NSPLIT)   // 512
#define PART_STRIDE (B_DIM * O_DIM)

typedef __attribute__((ext_vector_type(8))) short bf16x8;
typedef __attribute__((ext_vector_type(4))) float f32x4;
typedef __attribute__((ext_vector_type(4))) int   i32x4;

static __device__ __forceinline__ unsigned short f2bf(float f) {
    return __builtin_bit_cast(unsigned short, __float2bfloat16(f));
}

static __device__ __forceinline__ bf16x8 dequant8(const i32x4 qa, const i32x4 qb,
                                                  const float s) {
    const float c = -127.0f * s;
    bf16x8 v;
    v[0] = (short)f2bf(fmaf((float)qa[0], s, c));
    v[1] = (short)f2bf(fmaf((float)qa[1], s, c));
    v[2] = (short)f2bf(fmaf((float)qa[2], s, c));
    v[3] = (short)f2bf(fmaf((float)qa[3], s, c));
    v[4] = (short)f2bf(fmaf((float)qb[0], s, c));
    v[5] = (short)f2bf(fmaf((float)qb[1], s, c));
    v[6] = (short)f2bf(fmaf((float)qb[2], s, c));
    v[7] = (short)f2bf(fmaf((float)qb[3], s, c));
    return v;
}

__global__ __launch_bounds__(256, 3) void gemm_kernel(const float* __restrict__ x,
                                                      const int*   __restrict__ qw,
                                                      const float* __restrict__ scales,
                                                      float*       __restrict__ part) {
    __shared__ unsigned short x_s[B_DIM * KT];   // 32 KB, XOR-swizzled

    const int t    = threadIdx.x;
    const int wav  = t >> 6;
    const int lan  = t & 63;
    const int lrow = lan & 15;      // fragment row
    const int lq   = lan >> 4;      // lane quarter -> k sub-offset

    const int split  = blockIdx.x;                    // fastest-varying: k-split
    const int k_base = split * KT;
    const int o_row  = blockIdx.y * 64 + wav * 16 + lrow;

    const int* __restrict__ wq = qw + o_row * I_DIM + k_base + lq * 8;

    // 16 scales for this row's k-split (one per 32-k step)
    float sc[16];
    {
        const float4* sp = reinterpret_cast<const float4*>(&scales[o_row * NB + split * 16]);
#pragma unroll
        for (int j = 0; j < 4; ++j) {
            const float4 v = sp[j];
            sc[4 * j + 0] = v.x; sc[4 * j + 1] = v.y;
            sc[4 * j + 2] = v.z; sc[4 * j + 3] = v.w;
        }
    }

    // chunk = 64 k (2 MFMA k-steps); lane's W slice = 2x 32B contiguous runs
    i32x4 wa0, wb0, wc0, wd0, wa1, wb1, wc1, wd1, wa2, wb2, wc2, wd2;

#define LOADW(A, B, C, D, c) {                           \
        const int* wp = wq + (c) * 64;                   \
        A = *reinterpret_cast<const i32x4*>(wp);         \
        B = *reinterpret_cast<const i32x4*>(wp + 4);     \
        C = *reinterpret_cast<const i32x4*>(wp + 32);    \
        D = *reinterpret_cast<const i32x4*>(wp + 36); }

    // issue first 2 chunks before staging/barrier (they don't touch LDS)
    LOADW(wa0, wb0, wc0, wd0, 0)
    LOADW(wa1, wb1, wc1, wd1, 1)

    // ---- stage x once: f32 global -> bf16 swizzled LDS ----
    {
        const int m  = t >> 3;            // 0..31
        const int k0 = (t & 7) * 64;      // 0..448
        const float4* xv = reinterpret_cast<const float4*>(x + m * I_DIM + k_base + k0);
#pragma unroll
        for (int j = 0; j < 8; ++j) {
            const float4 va = xv[2 * j];
            const float4 vb = xv[2 * j + 1];
            bf16x8 v;
            v[0] = (short)f2bf(va.x); v[1] = (short)f2bf(va.y);
            v[2] = (short)f2bf(va.z); v[3] = (short)f2bf(va.w);
            v[4] = (short)f2bf(vb.x); v[5] = (short)f2bf(vb.y);
            v[6] = (short)f2bf(vb.z); v[7] = (short)f2bf(vb.w);
            const int addr = ((m * KT + k0 + j * 8) * 2) ^ ((m & 7) << 4);
            *reinterpret_cast<bf16x8*>(reinterpret_cast<char*>(x_s) + addr) = v;
        }
    }

    __syncthreads();

    f32x4 acc0 = {0.f, 0.f, 0.f, 0.f};   // m rows 0..15
    f32x4 acc1 = {0.f, 0.f, 0.f, 0.f};   // m rows 16..31
    const int swz = (lrow & 7) << 4;

#define CONSUME(A, B, C, D, c) {                                                              \
        const int kb = (c) * 64 + lq * 8;                                                     \
        const bf16x8 a0 = *reinterpret_cast<const bf16x8*>(                                   \
            reinterpret_cast<const char*>(x_s) + ((( lrow       * KT + kb) * 2) ^ swz));      \
        const bf16x8 a1 = *reinterpret_cast<const bf16x8*>(                                   \
            reinterpret_cast<const char*>(x_s) + ((((lrow + 16) * KT + kb) * 2) ^ swz));      \
        const bf16x8 bA = dequant8(A, B, sc[2 * (c)]);                                        \
        acc0 = __builtin_amdgcn_mfma_f32_16x16x32_bf16(a0, bA, acc0, 0, 0, 0);                \
        acc1 = __builtin_amdgcn_mfma_f32_16x16x32_bf16(a1, bA, acc1, 0, 0, 0);                \
        const bf16x8 a2 = *reinterpret_cast<const bf16x8*>(                                   \
            reinterpret_cast<const char*>(x_s) + ((( lrow       * KT + kb + 32) * 2) ^ swz)); \
        const bf16x8 a3 = *reinterpret_cast<const bf16x8*>(                                   \
            reinterpret_cast<const char*>(x_s) + ((((lrow + 16) * KT + kb + 32) * 2) ^ swz)); \
        const bf16x8 bB = dequant8(C, D, sc[2 * (c) + 1]);                                    \
        acc0 = __builtin_amdgcn_mfma_f32_16x16x32_bf16(a2, bB, acc0, 0, 0, 0);                \
        acc1 = __builtin_amdgcn_mfma_f32_16x16x32_bf16(a3, bB, acc1, 0, 0, 0); }

    // 8 chunks, 3 buffers: consume c with chunks c+1, c+2 in flight
    LOADW(wa2, wb2, wc2, wd2, 2)
    CONSUME(wa0, wb0, wc0, wd0, 0)
    LOADW(wa0, wb0, wc0, wd0, 3)
    CONSUME(wa1, wb1, wc1, wd1, 1)
    LOADW(wa1, wb1, wc1, wd1, 4)
    CONSUME(wa2, wb2, wc2, wd2, 2)
    LOADW(wa2, wb2, wc2, wd2, 5)
    CONSUME(wa0, wb0, wc0, wd0, 3)
    LOADW(wa0, wb0, wc0, wd0, 6)
    CONSUME(wa1, wb1, wc1, wd1, 4)
    LOADW(wa1, wb1, wc1, wd1, 7)
    CONSUME(wa2, wb2, wc2, wd2, 5)
    CONSUME(wa0, wb0, wc0, wd0, 6)
    CONSUME(wa1, wb1, wc1, wd1, 7)

#undef LOADW
#undef CONSUME

    // C/D layout: col = lane&15 (o), row = (lane>>4)*4 + reg (m)  [m89]
    float* pp = part + split * PART_STRIDE;
#pragma unroll
    for (int r = 0; r < 4; ++r) {
        const int m = lq * 4 + r;
        __builtin_nontemporal_store(acc0[r], &pp[m * O_DIM + o_row]);
        __builtin_nontemporal_store(acc1[r], &pp[(m + 16) * O_DIM + o_row]);
    }
}

// ---- k2: out = bias + sum of partials (float4, nontemporal partial reads) ----
__global__ __launch_bounds__(256) void reduce_kernel(const float* __restrict__ part,
                                                     const float* __restrict__ bias,
                                                     float* __restrict__ out) {
    const int idx = blockIdx.x * 256 + threadIdx.x;   // 0 .. 88063 (=32*11008/4)
    const int m   = idx / (O_DIM / 4);
    const int o4  = idx - m * (O_DIM / 4);

    f32x4 v = *reinterpret_cast<const f32x4*>(&bias[o4 * 4]);
#pragma unroll
    for (int s = 0; s < NSPLIT; ++s) {
        const f32x4 p = __builtin_nontemporal_load(
            reinterpret_cast<const f32x4*>(&part[s * PART_STRIDE + m * O_DIM + o4 * 4]));
        v[0] += p[0]; v[1] += p[1]; v[2] += p[2]; v[3] += p[3];
    }
    *reinterpret_cast<f32x4*>(&out[m * O_DIM + o4 * 4]) = v;
}

extern "C" void kernel_launch(void* const* d_in, const int* in_sizes, int n_in,
                              void* d_out, int out_size, void* d_ws, size_t ws_size,
                              hipStream_t stream) {
    const float* x      = (const float*)d_in[0];
    const int*   qw     = (const int*)d_in[1];
    const float* scales = (const float*)d_in[2];
    const float* bias   = (const float*)d_in[3];
    float*       out    = (float*)d_out;
    float*       part   = (float*)d_ws;              // 8 x 32 x 11008 f32 = 11.3 MB

    // k1: streaming dequant-MFMA GEMM, split-major dispatch
    hipLaunchKernelGGL(gemm_kernel, dim3(NSPLIT, O_DIM / 64), dim3(256), 0, stream,
                       x, qw, scales, part);

    // k2: reduce partials + bias
    hipLaunchKernelGGL(reduce_kernel, dim3((B_DIM * O_DIM / 4) / 256), dim3(256), 0, stream,
                       part, bias, out);
}

// Round 8
// 48.075 us; speedup vs baseline: 1.0494x; 1.0494x over previous
//
#include <hip/hip_runtime.h>
#include <hip/hip_bf16.h>

// Q8_0-style fused dequant + linear: y[32,11008] = x[32,4096] @ W^T + bias
// W[o,i] = (qweight[o,i] - 127) * scales[o, i/32]
//
// Round 8 = round-5 GEMM (proven, 47.1us incl. heavy reduce) + f16 partials
// in TRANSPOSED layout [split][o][m]:
//  - lane's 4 accs are consecutive m at fixed o -> pack 4x f16 (RTE) into one
//    8-byte uint2 store. NO sub-dword stores anywhere (round 7's 2-byte
//    nt stores failed; suspected write-combine tearing).
//  - no nontemporal: 11.3 MB partial buffer is L3-resident, reduce reads hit L3.
//  - reduce: thread-per-o, 16 splits x 4 contiguous u16x8 loads, f32 accum,
//    + bias, 32 coalesced stores.

#define O_DIM  11008
#define I_DIM  4096
#define NB     128                // scale blocks per o-row
#define B_DIM  32
#define NSPLIT 16
#define KT     (I_DIM / NSPLIT)   // 256
#define PART_STRIDE (O_DIM * B_DIM)   // ushorts per split partial, layout [o][m]

typedef __attribute__((ext_vector_type(8))) short bf16x8;
typedef __attribute__((ext_vector_type(8))) unsigned short u16x8;
typedef __attribute__((ext_vector_type(4))) float f32x4;
typedef __attribute__((ext_vector_type(4))) int   i32x4;

static __device__ __forceinline__ unsigned short f2bf(float f) {
    return __builtin_bit_cast(unsigned short, __float2bfloat16(f));
}

static __device__ __forceinline__ unsigned int pkf16(float a, float b) {
    const unsigned short ua = __builtin_bit_cast(unsigned short, (_Float16)a);
    const unsigned short ub = __builtin_bit_cast(unsigned short, (_Float16)b);
    return (unsigned int)ua | ((unsigned int)ub << 16);
}

static __device__ __forceinline__ bf16x8 dequant8(const i32x4 qa, const i32x4 qb,
                                                  const float s) {
    const float c = -127.0f * s;
    bf16x8 v;
    v[0] = (short)f2bf(fmaf((float)qa[0], s, c));
    v[1] = (short)f2bf(fmaf((float)qa[1], s, c));
    v[2] = (short)f2bf(fmaf((float)qa[2], s, c));
    v[3] = (short)f2bf(fmaf((float)qa[3], s, c));
    v[4] = (short)f2bf(fmaf((float)qb[0], s, c));
    v[5] = (short)f2bf(fmaf((float)qb[1], s, c));
    v[6] = (short)f2bf(fmaf((float)qb[2], s, c));
    v[7] = (short)f2bf(fmaf((float)qb[3], s, c));
    return v;
}

__global__ __launch_bounds__(256) void gemm_kernel(const float* __restrict__ x,
                                                   const int*   __restrict__ qw,
                                                   const float* __restrict__ scales,
                                                   unsigned short* __restrict__ part) {
    __shared__ unsigned short x_s[B_DIM * KT];   // 16 KB, XOR-swizzled

    const int t    = threadIdx.x;
    const int wav  = t >> 6;
    const int lan  = t & 63;
    const int lrow = lan & 15;      // fragment row
    const int lq   = lan >> 4;      // lane quarter -> k sub-offset

    const int split  = blockIdx.x;                    // fastest-varying: k-split
    const int k_base = split * KT;
    const int o_row  = blockIdx.y * 64 + wav * 16 + lrow;

    const int* __restrict__ wq = qw + o_row * I_DIM + k_base + lq * 8;

    // 8 scales for this row's k-split (one per 32-k step)
    float sc[8];
    {
        const float4* sp = reinterpret_cast<const float4*>(&scales[o_row * NB + split * 8]);
        const float4 s0 = sp[0], s1 = sp[1];
        sc[0] = s0.x; sc[1] = s0.y; sc[2] = s0.z; sc[3] = s0.w;
        sc[4] = s1.x; sc[5] = s1.y; sc[6] = s1.z; sc[7] = s1.w;
    }

    // chunk = 64 k (2 MFMA k-steps); lane's W slice = 2x 16B at +0/+16B
    i32x4 wa0, wb0, wc0, wd0, wa1, wb1, wc1, wd1, wa2, wb2, wc2, wd2;

#define LOADW(A, B, C, D, c) {                           \
        const int* wp = wq + (c) * 64;                   \
        A = *reinterpret_cast<const i32x4*>(wp);         \
        B = *reinterpret_cast<const i32x4*>(wp + 4);     \
        C = *reinterpret_cast<const i32x4*>(wp + 32);    \
        D = *reinterpret_cast<const i32x4*>(wp + 36); }

    // issue first 2 chunks before staging/barrier (they don't touch LDS)
    LOADW(wa0, wb0, wc0, wd0, 0)
    LOADW(wa1, wb1, wc1, wd1, 1)

    // ---- stage x once: f32 global -> bf16 swizzled LDS ----
    {
        const int m  = t >> 3;            // 0..31
        const int k0 = (t & 7) * 32;      // 0..224
        const float4* xv = reinterpret_cast<const float4*>(x + m * I_DIM + k_base + k0);
#pragma unroll
        for (int j = 0; j < 4; ++j) {
            const float4 va = xv[2 * j];
            const float4 vb = xv[2 * j + 1];
            bf16x8 v;
            v[0] = (short)f2bf(va.x); v[1] = (short)f2bf(va.y);
            v[2] = (short)f2bf(va.z); v[3] = (short)f2bf(va.w);
            v[4] = (short)f2bf(vb.x); v[5] = (short)f2bf(vb.y);
            v[6] = (short)f2bf(vb.z); v[7] = (short)f2bf(vb.w);
            const int addr = ((m * KT + k0 + j * 8) * 2) ^ ((m & 7) << 4);
            *reinterpret_cast<bf16x8*>(reinterpret_cast<char*>(x_s) + addr) = v;
        }
    }

    __syncthreads();

    f32x4 acc0 = {0.f, 0.f, 0.f, 0.f};   // m rows 0..15
    f32x4 acc1 = {0.f, 0.f, 0.f, 0.f};   // m rows 16..31
    const int swz = (lrow & 7) << 4;

#define CONSUME(A, B, C, D, c) {                                                              \
        const int kb = (c) * 64 + lq * 8;                                                     \
        const bf16x8 a0 = *reinterpret_cast<const bf16x8*>(                                   \
            reinterpret_cast<const char*>(x_s) + ((( lrow       * KT + kb) * 2) ^ swz));      \
        const bf16x8 a1 = *reinterpret_cast<const bf16x8*>(                                   \
            reinterpret_cast<const char*>(x_s) + ((((lrow + 16) * KT + kb) * 2) ^ swz));      \
        const bf16x8 bA = dequant8(A, B, sc[2 * (c)]);                                        \
        acc0 = __builtin_amdgcn_mfma_f32_16x16x32_bf16(a0, bA, acc0, 0, 0, 0);                \
        acc1 = __builtin_amdgcn_mfma_f32_16x16x32_bf16(a1, bA, acc1, 0, 0, 0);                \
        const bf16x8 a2 = *reinterpret_cast<const bf16x8*>(                                   \
            reinterpret_cast<const char*>(x_s) + ((( lrow       * KT + kb + 32) * 2) ^ swz)); \
        const bf16x8 a3 = *reinterpret_cast<const bf16x8*>(                                   \
            reinterpret_cast<const char*>(x_s) + ((((lrow + 16) * KT + kb + 32) * 2) ^ swz)); \
        const bf16x8 bB = dequant8(C, D, sc[2 * (c) + 1]);                                    \
        acc0 = __builtin_amdgcn_mfma_f32_16x16x32_bf16(a2, bB, acc0, 0, 0, 0);                \
        acc1 = __builtin_amdgcn_mfma_f32_16x16x32_bf16(a3, bB, acc1, 0, 0, 0); }

    // 4 chunks, 3 buffers: consume c with chunks c+1, c+2 in flight
    LOADW(wa2, wb2, wc2, wd2, 2)
    CONSUME(wa0, wb0, wc0, wd0, 0)
    LOADW(wa0, wb0, wc0, wd0, 3)
    CONSUME(wa1, wb1, wc1, wd1, 1)
    CONSUME(wa2, wb2, wc2, wd2, 2)
    CONSUME(wa0, wb0, wc0, wd0, 3)

#undef LOADW
#undef CONSUME

    // ---- epilogue: partials in [o][m] layout, 4x f16 packed per 8-byte store
    // C/D layout: col(o) = lane&15, row(m) = lq*4 + reg (acc0), +16 (acc1) [m89]
    unsigned short* pp = part + split * PART_STRIDE + o_row * B_DIM;
    const uint2 v0 = make_uint2(pkf16(acc0[0], acc0[1]), pkf16(acc0[2], acc0[3]));
    const uint2 v1 = make_uint2(pkf16(acc1[0], acc1[1]), pkf16(acc1[2], acc1[3]));
    *reinterpret_cast<uint2*>(&pp[lq * 4])      = v0;   // m = lq*4 .. lq*4+3
    *reinterpret_cast<uint2*>(&pp[16 + lq * 4]) = v1;   // m = 16+lq*4 ..
}

// ---- k2: thread-per-o reduce: out[m][o] = bias[o] + sum_s part[s][o][m] ----
__global__ __launch_bounds__(256) void reduce_kernel(const unsigned short* __restrict__ part,
                                                     const float* __restrict__ bias,
                                                     float* __restrict__ out) {
    const int o = blockIdx.x * 256 + threadIdx.x;   // 43 blocks = 11008 threads
    float v[B_DIM];
#pragma unroll
    for (int m = 0; m < B_DIM; ++m) v[m] = 0.f;

#pragma unroll
    for (int s = 0; s < NSPLIT; ++s) {
        const unsigned short* ps = part + s * PART_STRIDE + o * B_DIM;
#pragma unroll
        for (int g = 0; g < 4; ++g) {
            const u16x8 p = *reinterpret_cast<const u16x8*>(ps + g * 8);
#pragma unroll
            for (int j = 0; j < 8; ++j)
                v[g * 8 + j] += (float)__builtin_bit_cast(_Float16, (unsigned short)p[j]);
        }
    }

    const float b = bias[o];
#pragma unroll
    for (int m = 0; m < B_DIM; ++m)
        out[m * O_DIM + o] = v[m] + b;
}

extern "C" void kernel_launch(void* const* d_in, const int* in_sizes, int n_in,
                              void* d_out, int out_size, void* d_ws, size_t ws_size,
                              hipStream_t stream) {
    const float* x      = (const float*)d_in[0];
    const int*   qw     = (const int*)d_in[1];
    const float* scales = (const float*)d_in[2];
    const float* bias   = (const float*)d_in[3];
    float*       out    = (float*)d_out;
    unsigned short* part = (unsigned short*)d_ws;    // 16 x 11008 x 32 f16 = 11.3 MB

    // k1: streaming dequant-MFMA GEMM (round-5 config), split-major dispatch
    hipLaunchKernelGGL(gemm_kernel, dim3(NSPLIT, O_DIM / 64), dim3(256), 0, stream,
                       x, qw, scales, part);

    // k2: reduce partials + bias
    hipLaunchKernelGGL(reduce_kernel, dim3(O_DIM / 256), dim3(256), 0, stream,
                       part, bias, out);
}